// Round 4
// baseline (664.571 us; speedup 1.0000x reference)
//
#include <hip/hip_runtime.h>
#include <hip/hip_bf16.h>

typedef __attribute__((ext_vector_type(8))) short short8;
typedef __attribute__((ext_vector_type(4))) float f32x4;
typedef __attribute__((ext_vector_type(2))) unsigned int uint2v;

#define LOG2E 1.4426950408889634f
#define LN2   0.6931471805599453f

__device__ __forceinline__ unsigned short f2bf(float f) {
    union { float f; unsigned u; } v; v.f = f;
    unsigned u = v.u;
    u += 0x7fffu + ((u >> 16) & 1u);   // RNE, finite
    return (unsigned short)(u >> 16);
}
__device__ __forceinline__ float bf2f(unsigned short h) {
    union { unsigned u; float f; } v; v.u = ((unsigned)h) << 16;
    return v.f;
}
__device__ __forceinline__ unsigned pk_bf16(float a, float b) {
    __hip_bfloat162 t = __float22bfloat162_rn(float2{a, b});   // v_cvt_pk_bf16_f32
    union { __hip_bfloat162 b; unsigned u; } v; v.b = t;
    return v.u;
}

// ---------------------------------------------------------------------------
// Tile->column map (quad-interleaved): global tile t (0..15), frag col i:
//   phys col n = (t>>3)*128 + ((t>>2)&1)*64 + 4*i + (t&3)
// so tiles 4p..4p+3 of a col-half give each lane 4 ADJACENT phys cols
// -> b64 packed activation writes.
// Pack W0 (hi/lo split, K=9 pad 32, NKS=1), W1, W2 (NKS=8) into 16x16x32
// B-frag order: wp[((t*NKS+ks)*64+lane)*8+j] = W[k= ks*32+(lane>>4)*8+j][n].
// negc[l*256+n] = -log2(e)/(2*sigma^2).
// ---------------------------------------------------------------------------
__global__ void pack_kernel(const float* __restrict__ W0, const float* __restrict__ W1,
                            const float* __restrict__ W2,
                            const float* __restrict__ s0, const float* __restrict__ s1,
                            const float* __restrict__ s2,
                            unsigned short* __restrict__ wp, float* __restrict__ negc) {
    int tid = blockIdx.x * 256 + threadIdx.x;    // 0 .. 139263
    if (tid < 8192) {                            // W0: A rows [ph,ph,pl]/dim, B rows [wh,wl,wh]/dim
        int j = tid & 7, lane = (tid >> 3) & 63, t = tid >> 9;
        int k = ((lane >> 4) * 8) + j;           // 0..31
        int n = ((t >> 3) * 128) + (((t >> 2) & 1) * 64) + 4 * (lane & 15) + (t & 3);
        unsigned short v = 0;
        if (k < 9) {
            int d = k / 3, m = k - d * 3;        // m: 0->wh 1->wl 2->wh
            float w = W0[d * 256 + n];
            unsigned short wh = f2bf(w);
            v = (m == 1) ? f2bf(w - bf2f(wh)) : wh;
        }
        wp[tid] = v;
    } else if (tid < 139264) {
        int e = tid - 8192;
        const float* W = W1;
        if (e >= 65536) { W = W2; e -= 65536; }
        int j = e & 7, lane = (e >> 3) & 63, ks = (e >> 9) & 7, t = e >> 12;
        int k = ks * 32 + ((lane >> 4) * 8) + j;
        int n = ((t >> 3) * 128) + (((t >> 2) & 1) * 64) + 4 * (lane & 15) + (t & 3);
        wp[tid] = f2bf(W[k * 256 + n]);
    }
    if (tid < 768) {
        const float* s = (tid < 256) ? s0 : (tid < 512 ? s1 : s2);
        float sv = s[tid & 255];
        negc[tid] = -LOG2E / (2.0f * sv * sv);
    }
}

constexpr int ROWS = 64;     // rows per block (256 threads = 4 waves)
constexpr int HSTR = 264;    // h row stride, bf16 elems (+8 pad; 528 B, 16B-mult)
constexpr int ASTR = 40;     // A0 row stride (80 B: conflict-free b128 pattern)

// One MFMA layer. Wave = rgrp (wave>>1, rows rgrp*32..+31) x chalf (wave&1,
// cols chalf*128..+127). acc[2 rg][8 nt], nt -> col (nt>>2)*64 + 4*i16 + (nt&3).
template <int NKS, int SSTR>
__device__ __forceinline__ void layer(const unsigned short* __restrict__ src,
                                      const unsigned short* __restrict__ wpk,
                                      const float* __restrict__ bias,
                                      const float* __restrict__ ncp,
                                      unsigned short* __restrict__ hdst,
                                      int rgrp, int chalf, int i16, int q, bool presync) {
    f32x4 bb[2], np[2];
#pragma unroll
    for (int p = 0; p < 2; ++p) {
        int ce = chalf * 128 + p * 64 + 4 * i16;
        bb[p] = *(const f32x4*)(bias + ce);
        np[p] = *(const f32x4*)(ncp + ce);
    }
    f32x4 acc[2][8];
#pragma unroll
    for (int rg = 0; rg < 2; ++rg)
#pragma unroll
        for (int nt = 0; nt < 8; ++nt) {
            float b = bb[nt >> 2][nt & 3];
            acc[rg][nt] = f32x4{b, b, b, b};
        }
    const int lane = q * 16 + i16;
    const short8* wp8 = (const short8*)wpk;
    const unsigned short* abase = src + (rgrp * 32 + i16) * SSTR + q * 8;
#pragma unroll
    for (int ks = 0; ks < NKS; ++ks) {
        short8 wf[8];
#pragma unroll
        for (int s = 0; s < 8; ++s)
            wf[s] = wp8[((chalf * 8 + s) * NKS + ks) * 64 + lane];
#pragma unroll
        for (int rg = 0; rg < 2; ++rg) {
            short8 a = *(const short8*)(abase + rg * 16 * SSTR + ks * 32);
#pragma unroll
            for (int nt = 0; nt < 8; ++nt)
                acc[rg][nt] = __builtin_amdgcn_mfma_f32_16x16x32_bf16(a, wf[nt], acc[rg][nt], 0, 0, 0);
        }
    }
    if (presync) __syncthreads();   // all reads of hdst done before overwrite

    // Activation epilogue: 4 adjacent cols per (p) -> one ds_write_b64.
#pragma unroll
    for (int rg = 0; rg < 2; ++rg) {
        int rbase = rgrp * 32 + rg * 16 + q * 4;
#pragma unroll
        for (int p = 0; p < 2; ++p) {
            int col = chalf * 128 + p * 64 + 4 * i16;
#pragma unroll
            for (int rr = 0; rr < 4; ++rr) {
                float g0 = __builtin_amdgcn_exp2f(acc[rg][4*p+0][rr] * acc[rg][4*p+0][rr] * np[p][0]);
                float g1 = __builtin_amdgcn_exp2f(acc[rg][4*p+1][rr] * acc[rg][4*p+1][rr] * np[p][1]);
                float g2 = __builtin_amdgcn_exp2f(acc[rg][4*p+2][rr] * acc[rg][4*p+2][rr] * np[p][2]);
                float g3 = __builtin_amdgcn_exp2f(acc[rg][4*p+3][rr] * acc[rg][4*p+3][rr] * np[p][3]);
                uint2v v;
                v[0] = pk_bf16(g0, g1);
                v[1] = pk_bf16(g2, g3);
                *(uint2v*)&hdst[(rbase + rr) * HSTR + col] = v;
            }
        }
    }
    __syncthreads();
}

__global__ __launch_bounds__(256, 4) void mlp_kernel(
    const float* __restrict__ pos,
    const float* __restrict__ b0, const float* __restrict__ b1,
    const float* __restrict__ b2,
    const float* __restrict__ W3, const float* __restrict__ b3,
    const unsigned short* __restrict__ Wp,
    const float* __restrict__ negc,
    float* __restrict__ out)
{
    __shared__ unsigned short h[ROWS * HSTR];   // 33792 B
    __shared__ unsigned short A0[ROWS * ASTR];  // 5120 B   (total 38912 -> 4 blk/CU)

    const int tid  = threadIdx.x;
    const int lane = tid & 63;
    const int wave = tid >> 6;
    const int rgrp = wave >> 1, chalf = wave & 1;
    const int i16  = lane & 15, q = lane >> 4;
    const long row0 = (long)blockIdx.x * ROWS;

    // ---- build A0: row r = [p0h,p0h,p0l, p1h,p1h,p1l, p2h,p2h,p2l, 0...] ----
    if (tid < ROWS) {
        const float* pp = pos + (row0 + tid) * 3;
        float p0 = pp[0], p1 = pp[1], p2 = pp[2];
        short h0 = (short)f2bf(p0); short l0 = (short)f2bf(p0 - bf2f((unsigned short)h0));
        short h1 = (short)f2bf(p1); short l1 = (short)f2bf(p1 - bf2f((unsigned short)h1));
        short h2 = (short)f2bf(p2); short l2 = (short)f2bf(p2 - bf2f((unsigned short)h2));
        unsigned short* arow = A0 + tid * ASTR;
        *(short8*)(arow + 0)  = short8{h0, h0, l0, h1, h1, l1, h2, h2};
        *(short8*)(arow + 8)  = short8{l2, 0, 0, 0, 0, 0, 0, 0};
        *(short8*)(arow + 16) = short8{0, 0, 0, 0, 0, 0, 0, 0};
        *(short8*)(arow + 24) = short8{0, 0, 0, 0, 0, 0, 0, 0};
    }
    __syncthreads();

    // ---- layer 0 (MFMA K=32 hi/lo), layers 1,2 ----
    layer<1, ASTR>(A0, Wp, b0, negc, h, rgrp, chalf, i16, q, false);
    layer<8, HSTR>(h, Wp + 8192, b1, negc + 256, h, rgrp, chalf, i16, q, true);
    layer<8, HSTR>(h, Wp + 73728, b2, negc + 512, h, rgrp, chalf, i16, q, true);

    // ---- layer 4: dot(h_row, W3) + softplus(beta=1, thr=8) ----
    // 4 threads/row; thread qq sums col chunks (qq + 4i)*8 (bank-uniform).
    {
        int r = tid >> 2, qq = tid & 3;
        const unsigned short* hrow = h + r * HSTR;
        float s = 0.0f;
#pragma unroll
        for (int i = 0; i < 8; ++i) {
            int c = (qq + 4 * i) * 8;
            short8 hv = *(const short8*)(hrow + c);
            f32x4 wA = *(const f32x4*)(W3 + c);
            f32x4 wB = *(const f32x4*)(W3 + c + 4);
#pragma unroll
            for (int jj = 0; jj < 4; ++jj) {
                s = fmaf(bf2f((unsigned short)hv[jj]), wA[jj], s);
                s = fmaf(bf2f((unsigned short)hv[4 + jj]), wB[jj], s);
            }
        }
        s += __shfl_xor(s, 1);
        s += __shfl_xor(s, 2);
        if (qq == 0) {
            float x  = s + b3[0];
            float xm = fminf(x, 8.0f);
            float e  = __builtin_amdgcn_exp2f(xm * LOG2E);
            float sp = __builtin_amdgcn_logf(1.0f + e) * LN2;
            out[row0 + r] = (x > 8.0f) ? x : sp;
        }
    }
}

extern "C" void kernel_launch(void* const* d_in, const int* in_sizes, int n_in,
                              void* d_out, int out_size, void* d_ws, size_t ws_size,
                              hipStream_t stream) {
    const float* pos = (const float*)d_in[0];
    const float* W0  = (const float*)d_in[1];
    const float* b0  = (const float*)d_in[2];
    const float* W1  = (const float*)d_in[3];
    const float* b1  = (const float*)d_in[4];
    const float* W2  = (const float*)d_in[5];
    const float* b2  = (const float*)d_in[6];
    const float* W3  = (const float*)d_in[7];
    const float* b3  = (const float*)d_in[8];
    const float* s0  = (const float*)d_in[9];
    const float* s1  = (const float*)d_in[10];
    const float* s2  = (const float*)d_in[11];

    unsigned short* wp = (unsigned short*)d_ws;              // 139264 bf16
    float* negc = (float*)((char*)d_ws + 278528);            // 768 fp32

    pack_kernel<<<544, 256, 0, stream>>>(W0, W1, W2, s0, s1, s2, wp, negc);

    int nrows = in_sizes[0] / 3;          // 1048576
    int nblk  = nrows / ROWS;             // 16384
    mlp_kernel<<<nblk, 256, 0, stream>>>(pos, b0, b1, b2, W3, b3, wp, negc,
                                         (float*)d_out);
}

// Round 5
// 459.804 us; speedup vs baseline: 1.4453x; 1.4453x over previous
//
#include <hip/hip_runtime.h>
#include <hip/hip_bf16.h>

typedef __attribute__((ext_vector_type(8))) short short8;
typedef __attribute__((ext_vector_type(4))) float f32x4;
typedef __attribute__((ext_vector_type(2))) unsigned int uint2v;

#define LOG2E 1.4426950408889634f
#define LN2   0.6931471805599453f

__device__ __forceinline__ unsigned short f2bf(float f) {
    union { float f; unsigned u; } v; v.f = f;
    unsigned u = v.u;
    u += 0x7fffu + ((u >> 16) & 1u);   // RNE, finite
    return (unsigned short)(u >> 16);
}
__device__ __forceinline__ float bf2f(unsigned short h) {
    union { unsigned u; float f; } v; v.u = ((unsigned)h) << 16;
    return v.f;
}
__device__ __forceinline__ unsigned pk_bf16(float a, float b) {
    __hip_bfloat162 t = __float22bfloat162_rn(float2{a, b});   // v_cvt_pk_bf16_f32
    union { __hip_bfloat162 b; unsigned u; } v; v.b = t;
    return v.u;
}

// ---------------------------------------------------------------------------
// Tile->column map (quad-interleaved): global tile t (0..15), frag col i:
//   phys col n = (t>>3)*128 + ((t>>2)&1)*64 + 4*i + (t&3)
// Pack W0 (hi/lo split, K=9 pad 32, NKS=1), W1, W2 (NKS=8) into 16x16x32
// B-frag order: wp[((t*NKS+ks)*64+lane)*8+j] = W[k= ks*32+(lane>>4)*8+j][n].
// negc[l*256+n] = -log2(e)/(2*sigma^2).
// ---------------------------------------------------------------------------
__global__ void pack_kernel(const float* __restrict__ W0, const float* __restrict__ W1,
                            const float* __restrict__ W2,
                            const float* __restrict__ s0, const float* __restrict__ s1,
                            const float* __restrict__ s2,
                            unsigned short* __restrict__ wp, float* __restrict__ negc) {
    int tid = blockIdx.x * 256 + threadIdx.x;    // 0 .. 139263
    if (tid < 8192) {                            // W0: A rows [ph,ph,pl]/dim, B rows [wh,wl,wh]/dim
        int j = tid & 7, lane = (tid >> 3) & 63, t = tid >> 9;
        int k = ((lane >> 4) * 8) + j;           // 0..31
        int n = ((t >> 3) * 128) + (((t >> 2) & 1) * 64) + 4 * (lane & 15) + (t & 3);
        unsigned short v = 0;
        if (k < 9) {
            int d = k / 3, m = k - d * 3;        // m: 0->wh 1->wl 2->wh
            float w = W0[d * 256 + n];
            unsigned short wh = f2bf(w);
            v = (m == 1) ? f2bf(w - bf2f(wh)) : wh;
        }
        wp[tid] = v;
    } else if (tid < 139264) {
        int e = tid - 8192;
        const float* W = W1;
        if (e >= 65536) { W = W2; e -= 65536; }
        int j = e & 7, lane = (e >> 3) & 63, ks = (e >> 9) & 7, t = e >> 12;
        int k = ks * 32 + ((lane >> 4) * 8) + j;
        int n = ((t >> 3) * 128) + (((t >> 2) & 1) * 64) + 4 * (lane & 15) + (t & 3);
        wp[tid] = f2bf(W[k * 256 + n]);
    }
    if (tid < 768) {
        const float* s = (tid < 256) ? s0 : (tid < 512 ? s1 : s2);
        float sv = s[tid & 255];
        negc[tid] = -LOG2E / (2.0f * sv * sv);
    }
}

constexpr int ROWS = 64;     // rows per block (256 threads = 4 waves)
constexpr int HSTR = 264;    // h row stride, bf16 elems (+8 pad; 528 B)
constexpr int ASTR = 40;     // A0 row stride (80 B)

// One MFMA layer. Wave = rgrp (rows rgrp*32..+31) x chalf (cols chalf*128..+127).
// acc[rg][nt]: nt -> col chalf*128 + (nt>>2)*64 + 4*i16 + (nt&3).
// Spill-free schedule: per ks read 2 A-frags, then stream 8 W-frags (transient).
// Bias folded into epilogue so the hot loop carries only acc + a + wf.
template <int NKS, int SSTR>
__device__ __forceinline__ void layer(const unsigned short* __restrict__ src,
                                      const unsigned short* __restrict__ wpk,
                                      const float* __restrict__ bias,
                                      const float* __restrict__ ncp,
                                      unsigned short* __restrict__ hdst,
                                      int rgrp, int chalf, int i16, int q, bool presync) {
    f32x4 acc[2][8];
#pragma unroll
    for (int rg = 0; rg < 2; ++rg)
#pragma unroll
        for (int nt = 0; nt < 8; ++nt)
            acc[rg][nt] = f32x4{0.f, 0.f, 0.f, 0.f};

    const int lane = q * 16 + i16;
    const short8* wp8 = (const short8*)wpk + (chalf * 8 * NKS) * 64 + lane;
    const unsigned short* abase = src + (rgrp * 32 + i16) * SSTR + q * 8;
#pragma unroll
    for (int ks = 0; ks < NKS; ++ks) {
        short8 a0 = *(const short8*)(abase + ks * 32);
        short8 a1 = *(const short8*)(abase + 16 * SSTR + ks * 32);
#pragma unroll
        for (int s = 0; s < 8; ++s) {
            short8 wf = wp8[(s * NKS + ks) * 64];
            acc[0][s] = __builtin_amdgcn_mfma_f32_16x16x32_bf16(a0, wf, acc[0][s], 0, 0, 0);
            acc[1][s] = __builtin_amdgcn_mfma_f32_16x16x32_bf16(a1, wf, acc[1][s], 0, 0, 0);
        }
    }
    if (presync) __syncthreads();   // all reads of hdst done before overwrite

    // Epilogue: bias add + gauss; 4 adjacent cols -> one ds_write_b64.
#pragma unroll
    for (int p = 0; p < 2; ++p) {
        const int ce = chalf * 128 + p * 64 + 4 * i16;
        const f32x4 bb = *(const f32x4*)(bias + ce);
        const f32x4 np = *(const f32x4*)(ncp + ce);
#pragma unroll
        for (int rg = 0; rg < 2; ++rg) {
            int rbase = rgrp * 32 + rg * 16 + q * 4;
#pragma unroll
            for (int rr = 0; rr < 4; ++rr) {
                float x0 = acc[rg][4*p+0][rr] + bb[0];
                float x1 = acc[rg][4*p+1][rr] + bb[1];
                float x2 = acc[rg][4*p+2][rr] + bb[2];
                float x3 = acc[rg][4*p+3][rr] + bb[3];
                float g0 = __builtin_amdgcn_exp2f(x0 * x0 * np[0]);
                float g1 = __builtin_amdgcn_exp2f(x1 * x1 * np[1]);
                float g2 = __builtin_amdgcn_exp2f(x2 * x2 * np[2]);
                float g3 = __builtin_amdgcn_exp2f(x3 * x3 * np[3]);
                uint2v v;
                v[0] = pk_bf16(g0, g1);
                v[1] = pk_bf16(g2, g3);
                *(uint2v*)&hdst[(rbase + rr) * HSTR + ce] = v;
            }
        }
    }
    __syncthreads();
}

__global__ __launch_bounds__(256, 4) void mlp_kernel(
    const float* __restrict__ pos,
    const float* __restrict__ b0, const float* __restrict__ b1,
    const float* __restrict__ b2,
    const float* __restrict__ W3, const float* __restrict__ b3,
    const unsigned short* __restrict__ Wp,
    const float* __restrict__ negc,
    float* __restrict__ out)
{
    __shared__ unsigned short h[ROWS * HSTR];   // 33792 B
    __shared__ unsigned short A0[ROWS * ASTR];  // 5120 B  (38912 total -> 4 blk/CU)

    const int tid  = threadIdx.x;
    const int lane = tid & 63;
    const int wave = tid >> 6;
    const int rgrp = wave >> 1, chalf = wave & 1;
    const int i16  = lane & 15, q = lane >> 4;
    const long row0 = (long)blockIdx.x * ROWS;

    // ---- build A0: row r = [p0h,p0h,p0l, p1h,p1h,p1l, p2h,p2h,p2l, 0...] ----
    if (tid < ROWS) {
        const float* pp = pos + (row0 + tid) * 3;
        float p0 = pp[0], p1 = pp[1], p2 = pp[2];
        short h0 = (short)f2bf(p0); short l0 = (short)f2bf(p0 - bf2f((unsigned short)h0));
        short h1 = (short)f2bf(p1); short l1 = (short)f2bf(p1 - bf2f((unsigned short)h1));
        short h2 = (short)f2bf(p2); short l2 = (short)f2bf(p2 - bf2f((unsigned short)h2));
        unsigned short* arow = A0 + tid * ASTR;
        *(short8*)(arow + 0)  = short8{h0, h0, l0, h1, h1, l1, h2, h2};
        *(short8*)(arow + 8)  = short8{l2, 0, 0, 0, 0, 0, 0, 0};
        *(short8*)(arow + 16) = short8{0, 0, 0, 0, 0, 0, 0, 0};
        *(short8*)(arow + 24) = short8{0, 0, 0, 0, 0, 0, 0, 0};
    }
    __syncthreads();

    // ---- layer 0 (MFMA K=32 hi/lo), layers 1,2 ----
    layer<1, ASTR>(A0, Wp, b0, negc, h, rgrp, chalf, i16, q, false);
    layer<8, HSTR>(h, Wp + 8192, b1, negc + 256, h, rgrp, chalf, i16, q, true);
    layer<8, HSTR>(h, Wp + 73728, b2, negc + 512, h, rgrp, chalf, i16, q, true);

    // ---- layer 4: dot(h_row, W3) + softplus(beta=1, thr=8) ----
    {
        int r = tid >> 2, qq = tid & 3;
        const unsigned short* hrow = h + r * HSTR;
        float s = 0.0f;
#pragma unroll
        for (int i = 0; i < 8; ++i) {
            int c = (qq + 4 * i) * 8;
            short8 hv = *(const short8*)(hrow + c);
            f32x4 wA = *(const f32x4*)(W3 + c);
            f32x4 wB = *(const f32x4*)(W3 + c + 4);
#pragma unroll
            for (int jj = 0; jj < 4; ++jj) {
                s = fmaf(bf2f((unsigned short)hv[jj]), wA[jj], s);
                s = fmaf(bf2f((unsigned short)hv[4 + jj]), wB[jj], s);
            }
        }
        s += __shfl_xor(s, 1);
        s += __shfl_xor(s, 2);
        if (qq == 0) {
            float x  = s + b3[0];
            float xm = fminf(x, 8.0f);
            float e  = __builtin_amdgcn_exp2f(xm * LOG2E);
            float sp = __builtin_amdgcn_logf(1.0f + e) * LN2;
            out[row0 + r] = (x > 8.0f) ? x : sp;
        }
    }
}

extern "C" void kernel_launch(void* const* d_in, const int* in_sizes, int n_in,
                              void* d_out, int out_size, void* d_ws, size_t ws_size,
                              hipStream_t stream) {
    const float* pos = (const float*)d_in[0];
    const float* W0  = (const float*)d_in[1];
    const float* b0  = (const float*)d_in[2];
    const float* W1  = (const float*)d_in[3];
    const float* b1  = (const float*)d_in[4];
    const float* W2  = (const float*)d_in[5];
    const float* b2  = (const float*)d_in[6];
    const float* W3  = (const float*)d_in[7];
    const float* b3  = (const float*)d_in[8];
    const float* s0  = (const float*)d_in[9];
    const float* s1  = (const float*)d_in[10];
    const float* s2  = (const float*)d_in[11];

    unsigned short* wp = (unsigned short*)d_ws;              // 139264 bf16
    float* negc = (float*)((char*)d_ws + 278528);            // 768 fp32

    pack_kernel<<<544, 256, 0, stream>>>(W0, W1, W2, s0, s1, s2, wp, negc);

    int nrows = in_sizes[0] / 3;          // 1048576
    int nblk  = nrows / ROWS;             // 16384
    mlp_kernel<<<nblk, 256, 0, stream>>>(pos, b0, b1, b2, W3, b3, wp, negc,
                                         (float*)d_out);
}

// Round 6
// 455.588 us; speedup vs baseline: 1.4587x; 1.0093x over previous
//
#include <hip/hip_runtime.h>
#include <hip/hip_bf16.h>

typedef __attribute__((ext_vector_type(8))) short short8;
typedef __attribute__((ext_vector_type(4))) float f32x4;
typedef __attribute__((ext_vector_type(2))) unsigned int uint2v;

#define LOG2E 1.4426950408889634f
#define LN2   0.6931471805599453f

__device__ __forceinline__ unsigned short f2bf(float f) {
    union { float f; unsigned u; } v; v.f = f;
    unsigned u = v.u;
    u += 0x7fffu + ((u >> 16) & 1u);   // RNE, finite
    return (unsigned short)(u >> 16);
}
__device__ __forceinline__ float bf2f(unsigned short h) {
    union { unsigned u; float f; } v; v.u = ((unsigned)h) << 16;
    return v.f;
}
__device__ __forceinline__ unsigned pk_bf16(float a, float b) {
    __hip_bfloat162 t = __float22bfloat162_rn(float2{a, b});   // v_cvt_pk_bf16_f32
    union { __hip_bfloat162 b; unsigned u; } v; v.b = t;
    return v.u;
}

// ---------------------------------------------------------------------------
// Tile->column map (quad-interleaved): global tile t (0..15), frag col i:
//   phys col n = (t>>3)*128 + ((t>>2)&1)*64 + 4*i + (t&3)
// Pack W0 (hi/lo split, K=9 pad 32, NKS=1), W1, W2 (NKS=8) into 16x16x32
// B-frag order: wp[((t*NKS+ks)*64+lane)*8+j] = W[k= ks*32+(lane>>4)*8+j][n].
// negc[l*256+n] = -log2(e)/(2*sigma^2).
// ---------------------------------------------------------------------------
__global__ void pack_kernel(const float* __restrict__ W0, const float* __restrict__ W1,
                            const float* __restrict__ W2,
                            const float* __restrict__ s0, const float* __restrict__ s1,
                            const float* __restrict__ s2,
                            unsigned short* __restrict__ wp, float* __restrict__ negc) {
    int tid = blockIdx.x * 256 + threadIdx.x;    // 0 .. 139263
    if (tid < 8192) {                            // W0: A rows [ph,ph,pl]/dim, B rows [wh,wl,wh]/dim
        int j = tid & 7, lane = (tid >> 3) & 63, t = tid >> 9;
        int k = ((lane >> 4) * 8) + j;           // 0..31
        int n = ((t >> 3) * 128) + (((t >> 2) & 1) * 64) + 4 * (lane & 15) + (t & 3);
        unsigned short v = 0;
        if (k < 9) {
            int d = k / 3, m = k - d * 3;        // m: 0->wh 1->wl 2->wh
            float w = W0[d * 256 + n];
            unsigned short wh = f2bf(w);
            v = (m == 1) ? f2bf(w - bf2f(wh)) : wh;
        }
        wp[tid] = v;
    } else if (tid < 139264) {
        int e = tid - 8192;
        const float* W = W1;
        if (e >= 65536) { W = W2; e -= 65536; }
        int j = e & 7, lane = (e >> 3) & 63, ks = (e >> 9) & 7, t = e >> 12;
        int k = ks * 32 + ((lane >> 4) * 8) + j;
        int n = ((t >> 3) * 128) + (((t >> 2) & 1) * 64) + 4 * (lane & 15) + (t & 3);
        wp[tid] = f2bf(W[k * 256 + n]);
    }
    if (tid < 768) {
        const float* s = (tid < 256) ? s0 : (tid < 512 ? s1 : s2);
        float sv = s[tid & 255];
        negc[tid] = -LOG2E / (2.0f * sv * sv);
    }
}

constexpr int ROWS = 64;     // rows per block (256 threads = 4 waves)
constexpr int HSTR = 264;    // h row stride, bf16 elems (+8 pad; 528 B)
constexpr int ASTR = 40;     // A0 row stride (80 B)

// One MFMA layer. Wave = rgrp (rows rgrp*32..+31) x chalf (cols chalf*128..+127).
// acc[rg][nt]: nt -> col chalf*128 + (nt>>2)*64 + 4*i16 + (nt&3).
// Software-pipelined: weight frags prefetched one 4-group ahead (wcur/wnxt),
// A-frags one ks ahead. Activations computed into regs BEFORE the presync
// barrier so only the ds_writes sit between the two barriers.
template <int NKS, int SSTR>
__device__ __forceinline__ void layer(const unsigned short* __restrict__ src,
                                      const unsigned short* __restrict__ wpk,
                                      const float* __restrict__ bias,
                                      const float* __restrict__ ncp,
                                      unsigned short* __restrict__ hdst,
                                      int rgrp, int chalf, int i16, int q, bool presync) {
    f32x4 acc[2][8];
#pragma unroll
    for (int rg = 0; rg < 2; ++rg)
#pragma unroll
        for (int nt = 0; nt < 8; ++nt)
            acc[rg][nt] = f32x4{0.f, 0.f, 0.f, 0.f};

    const int lane = q * 16 + i16;
    const short8* wp8 = (const short8*)wpk + (chalf * 8 * NKS) * 64 + lane;
    const unsigned short* abase = src + (rgrp * 32 + i16) * SSTR + q * 8;

    short8 wcur[4], wnxt[4];
    short8 a0 = *(const short8*)(abase);
    short8 a1 = *(const short8*)(abase + 16 * SSTR);
    short8 na0 = a0, na1 = a1;
#pragma unroll
    for (int s = 0; s < 4; ++s) wcur[s] = wp8[(s * NKS) * 64];

#pragma unroll
    for (int ks = 0; ks < NKS; ++ks) {
#pragma unroll
        for (int g = 0; g < 2; ++g) {
            // issue prefetches for the NEXT group before consuming current
            if (g == 0) {
#pragma unroll
                for (int s = 0; s < 4; ++s)
                    wnxt[s] = wp8[((4 + s) * NKS + ks) * 64];
            } else if (ks + 1 < NKS) {
#pragma unroll
                for (int s = 0; s < 4; ++s)
                    wnxt[s] = wp8[(s * NKS + ks + 1) * 64];
                na0 = *(const short8*)(abase + (ks + 1) * 32);
                na1 = *(const short8*)(abase + 16 * SSTR + (ks + 1) * 32);
            }
#pragma unroll
            for (int s = 0; s < 4; ++s) {
                int nt = g * 4 + s;
                acc[0][nt] = __builtin_amdgcn_mfma_f32_16x16x32_bf16(a0, wcur[s], acc[0][nt], 0, 0, 0);
                acc[1][nt] = __builtin_amdgcn_mfma_f32_16x16x32_bf16(a1, wcur[s], acc[1][nt], 0, 0, 0);
            }
#pragma unroll
            for (int s = 0; s < 4; ++s) wcur[s] = wnxt[s];
            if (g == 1) { a0 = na0; a1 = na1; }
        }
    }

    // ---- activation math BEFORE barrier (acc -> packed bf16 pairs) ----
    uint2v av[2][2][4];
#pragma unroll
    for (int p = 0; p < 2; ++p) {
        const int ce = chalf * 128 + p * 64 + 4 * i16;
        const f32x4 bb = *(const f32x4*)(bias + ce);
        const f32x4 np = *(const f32x4*)(ncp + ce);
#pragma unroll
        for (int rg = 0; rg < 2; ++rg)
#pragma unroll
            for (int rr = 0; rr < 4; ++rr) {
                float x0 = acc[rg][4*p+0][rr] + bb[0];
                float x1 = acc[rg][4*p+1][rr] + bb[1];
                float x2 = acc[rg][4*p+2][rr] + bb[2];
                float x3 = acc[rg][4*p+3][rr] + bb[3];
                float g0 = __builtin_amdgcn_exp2f(x0 * x0 * np[0]);
                float g1 = __builtin_amdgcn_exp2f(x1 * x1 * np[1]);
                float g2 = __builtin_amdgcn_exp2f(x2 * x2 * np[2]);
                float g3 = __builtin_amdgcn_exp2f(x3 * x3 * np[3]);
                uint2v v;
                v[0] = pk_bf16(g0, g1);
                v[1] = pk_bf16(g2, g3);
                av[p][rg][rr] = v;
            }
    }
    if (presync) __syncthreads();   // all reads of hdst done before overwrite
#pragma unroll
    for (int p = 0; p < 2; ++p) {
        const int ce = chalf * 128 + p * 64 + 4 * i16;
#pragma unroll
        for (int rg = 0; rg < 2; ++rg) {
            int rbase = rgrp * 32 + rg * 16 + q * 4;
#pragma unroll
            for (int rr = 0; rr < 4; ++rr)
                *(uint2v*)&hdst[(rbase + rr) * HSTR + ce] = av[p][rg][rr];
        }
    }
    __syncthreads();
}

__global__ __launch_bounds__(256, 3) void mlp_kernel(
    const float* __restrict__ pos,
    const float* __restrict__ b0, const float* __restrict__ b1,
    const float* __restrict__ b2,
    const float* __restrict__ W3, const float* __restrict__ b3,
    const unsigned short* __restrict__ Wp,
    const float* __restrict__ negc,
    float* __restrict__ out)
{
    __shared__ unsigned short h[ROWS * HSTR];   // 33792 B
    __shared__ unsigned short A0[ROWS * ASTR];  // 5120 B

    const int tid  = threadIdx.x;
    const int lane = tid & 63;
    const int wave = tid >> 6;
    const int rgrp = wave >> 1, chalf = wave & 1;
    const int i16  = lane & 15, q = lane >> 4;
    const long row0 = (long)blockIdx.x * ROWS;

    // ---- build A0: row r = [p0h,p0h,p0l, p1h,p1h,p1l, p2h,p2h,p2l, 0...] ----
    if (tid < ROWS) {
        const float* pp = pos + (row0 + tid) * 3;
        float p0 = pp[0], p1 = pp[1], p2 = pp[2];
        short h0 = (short)f2bf(p0); short l0 = (short)f2bf(p0 - bf2f((unsigned short)h0));
        short h1 = (short)f2bf(p1); short l1 = (short)f2bf(p1 - bf2f((unsigned short)h1));
        short h2 = (short)f2bf(p2); short l2 = (short)f2bf(p2 - bf2f((unsigned short)h2));
        unsigned short* arow = A0 + tid * ASTR;
        *(short8*)(arow + 0)  = short8{h0, h0, l0, h1, h1, l1, h2, h2};
        *(short8*)(arow + 8)  = short8{l2, 0, 0, 0, 0, 0, 0, 0};
        *(short8*)(arow + 16) = short8{0, 0, 0, 0, 0, 0, 0, 0};
        *(short8*)(arow + 24) = short8{0, 0, 0, 0, 0, 0, 0, 0};
    }
    __syncthreads();

    // ---- layer 0 (MFMA K=32 hi/lo), layers 1,2 ----
    layer<1, ASTR>(A0, Wp, b0, negc, h, rgrp, chalf, i16, q, false);
    layer<8, HSTR>(h, Wp + 8192, b1, negc + 256, h, rgrp, chalf, i16, q, true);
    layer<8, HSTR>(h, Wp + 73728, b2, negc + 512, h, rgrp, chalf, i16, q, true);

    // ---- layer 4: dot(h_row, W3) + softplus(beta=1, thr=8) ----
    {
        int r = tid >> 2, qq = tid & 3;
        const unsigned short* hrow = h + r * HSTR;
        float s = 0.0f;
#pragma unroll
        for (int i = 0; i < 8; ++i) {
            int c = (qq + 4 * i) * 8;
            short8 hv = *(const short8*)(hrow + c);
            f32x4 wA = *(const f32x4*)(W3 + c);
            f32x4 wB = *(const f32x4*)(W3 + c + 4);
#pragma unroll
            for (int jj = 0; jj < 4; ++jj) {
                s = fmaf(bf2f((unsigned short)hv[jj]), wA[jj], s);
                s = fmaf(bf2f((unsigned short)hv[4 + jj]), wB[jj], s);
            }
        }
        s += __shfl_xor(s, 1);
        s += __shfl_xor(s, 2);
        if (qq == 0) {
            float x  = s + b3[0];
            float xm = fminf(x, 8.0f);
            float e  = __builtin_amdgcn_exp2f(xm * LOG2E);
            float sp = __builtin_amdgcn_logf(1.0f + e) * LN2;
            out[row0 + r] = (x > 8.0f) ? x : sp;
        }
    }
}

extern "C" void kernel_launch(void* const* d_in, const int* in_sizes, int n_in,
                              void* d_out, int out_size, void* d_ws, size_t ws_size,
                              hipStream_t stream) {
    const float* pos = (const float*)d_in[0];
    const float* W0  = (const float*)d_in[1];
    const float* b0  = (const float*)d_in[2];
    const float* W1  = (const float*)d_in[3];
    const float* b1  = (const float*)d_in[4];
    const float* W2  = (const float*)d_in[5];
    const float* b2  = (const float*)d_in[6];
    const float* W3  = (const float*)d_in[7];
    const float* b3  = (const float*)d_in[8];
    const float* s0  = (const float*)d_in[9];
    const float* s1  = (const float*)d_in[10];
    const float* s2  = (const float*)d_in[11];

    unsigned short* wp = (unsigned short*)d_ws;              // 139264 bf16
    float* negc = (float*)((char*)d_ws + 278528);            // 768 fp32

    pack_kernel<<<544, 256, 0, stream>>>(W0, W1, W2, s0, s1, s2, wp, negc);

    int nrows = in_sizes[0] / 3;          // 1048576
    int nblk  = nrows / ROWS;             // 16384
    mlp_kernel<<<nblk, 256, 0, stream>>>(pos, b0, b1, b2, W3, b3, wp, negc,
                                         (float*)d_out);
}

// Round 7
// 398.220 us; speedup vs baseline: 1.6689x; 1.1441x over previous
//
#include <hip/hip_runtime.h>
#include <hip/hip_bf16.h>

typedef __attribute__((ext_vector_type(8))) short short8;
typedef __attribute__((ext_vector_type(4))) float f32x4;
typedef __attribute__((ext_vector_type(2))) unsigned int uint2v;

#define LOG2E 1.4426950408889634f
#define LN2   0.6931471805599453f

__device__ __forceinline__ unsigned short f2bf(float f) {
    union { float f; unsigned u; } v; v.f = f;
    unsigned u = v.u;
    u += 0x7fffu + ((u >> 16) & 1u);   // RNE, finite
    return (unsigned short)(u >> 16);
}
__device__ __forceinline__ float bf2f(unsigned short h) {
    union { unsigned u; float f; } v; v.u = ((unsigned)h) << 16;
    return v.f;
}
__device__ __forceinline__ unsigned pk_bf16(float a, float b) {
    __hip_bfloat162 t = __float22bfloat162_rn(float2{a, b});   // v_cvt_pk_bf16_f32
    union { __hip_bfloat162 b; unsigned u; } v; v.b = t;
    return v.u;
}

// ---------------------------------------------------------------------------
// Wave tile = 64 rows x 64 cols. Wave w owns phys cols [w*64, w*64+64).
// Tile->column map: col tile ct (0..3), frag col i: phys n = w*64 + 4*i + ct
// (4 adjacent phys cols per lane -> b64 activation writes).
// Pack order per layer: frag-set index ((w*NKS + ks)*4 + ct) -> a wave's
// layer slice is one contiguous 32 KB stream.
//   wp[(((w*NKS+ks)*4+ct)*64 + lane)*8 + j] = W[k][n],
//   k = ks*32 + (lane>>4)*8 + j,  n = w*64 + 4*(lane&15) + ct.
// W0: hi/lo split rows [wh,wl,wh] per input dim (K=9 pad 32, NKS=1).
// negc[l*256+n] = -log2(e)/(2*sigma^2).
// ---------------------------------------------------------------------------
__global__ void pack_kernel(const float* __restrict__ W0, const float* __restrict__ W1,
                            const float* __restrict__ W2,
                            const float* __restrict__ s0, const float* __restrict__ s1,
                            const float* __restrict__ s2,
                            unsigned short* __restrict__ wp, float* __restrict__ negc) {
    int tid = blockIdx.x * 256 + threadIdx.x;    // 0 .. 139263
    if (tid < 8192) {                            // W0 (NKS=1)
        int j = tid & 7, lane = (tid >> 3) & 63, ct = (tid >> 9) & 3, w = tid >> 11;
        int k = ((lane >> 4) * 8) + j;           // 0..31
        int n = w * 64 + 4 * (lane & 15) + ct;
        unsigned short v = 0;
        if (k < 9) {
            int d = k / 3, m = k - d * 3;        // m: 0->wh 1->wl 2->wh
            float wv = W0[d * 256 + n];
            unsigned short wh = f2bf(wv);
            v = (m == 1) ? f2bf(wv - bf2f(wh)) : wh;
        }
        wp[tid] = v;
    } else if (tid < 139264) {                   // W1 / W2 (NKS=8)
        int e = tid - 8192;
        const float* W = W1;
        if (e >= 65536) { W = W2; e -= 65536; }
        int j = e & 7, lane = (e >> 3) & 63, ct = (e >> 9) & 3, ks = (e >> 11) & 7, w = e >> 14;
        int k = ks * 32 + ((lane >> 4) * 8) + j;
        int n = w * 64 + 4 * (lane & 15) + ct;
        wp[tid] = f2bf(W[k * 256 + n]);
    }
    if (tid < 768) {
        const float* s = (tid < 256) ? s0 : (tid < 512 ? s1 : s2);
        float sv = s[tid & 255];
        negc[tid] = -LOG2E / (2.0f * sv * sv);
    }
}

constexpr int ROWS = 64;     // rows per block (256 threads = 4 waves)
constexpr int HSTR = 264;    // h row stride, bf16 elems (+8 pad; 528 B)
constexpr int ASTR = 40;     // A0 row stride (80 B)

// One MFMA layer. Each wave: all 64 rows x its 64 cols. Per ks: 4 A-frags
// (rg) + 4 W-frags (ct, contiguous stream) -> 16 MFMAs (each load feeds 4).
// acc[rg][ct]; activations packed to regs BEFORE the presync barrier.
template <int NKS, int SSTR>
__device__ __forceinline__ void layer(const unsigned short* __restrict__ src,
                                      const unsigned short* __restrict__ wpk,
                                      const float* __restrict__ bias,
                                      const float* __restrict__ ncp,
                                      unsigned short* __restrict__ hdst,
                                      int w, int i16, int q, bool presync) {
    f32x4 acc[4][4];
#pragma unroll
    for (int rg = 0; rg < 4; ++rg)
#pragma unroll
        for (int ct = 0; ct < 4; ++ct)
            acc[rg][ct] = f32x4{0.f, 0.f, 0.f, 0.f};

    const int lane = q * 16 + i16;
    const short8* wp8 = (const short8*)wpk + (w * NKS * 4) * 64 + lane;
    const unsigned short* abase = src + i16 * SSTR + q * 8;

#pragma unroll
    for (int ks = 0; ks < NKS; ++ks) {
        short8 a[4];
#pragma unroll
        for (int rg = 0; rg < 4; ++rg)
            a[rg] = *(const short8*)(abase + rg * 16 * SSTR + ks * 32);
#pragma unroll
        for (int ct = 0; ct < 4; ++ct) {
            short8 wf = wp8[(ks * 4 + ct) * 64];
#pragma unroll
            for (int rg = 0; rg < 4; ++rg)
                acc[rg][ct] = __builtin_amdgcn_mfma_f32_16x16x32_bf16(a[rg], wf, acc[rg][ct], 0, 0, 0);
        }
    }

    // ---- activation math BEFORE barrier ----
    const int ce = w * 64 + 4 * i16;
    const f32x4 bb = *(const f32x4*)(bias + ce);
    const f32x4 np = *(const f32x4*)(ncp + ce);
    uint2v av[4][4];
#pragma unroll
    for (int rg = 0; rg < 4; ++rg)
#pragma unroll
        for (int rr = 0; rr < 4; ++rr) {
            float x0 = acc[rg][0][rr] + bb[0];
            float x1 = acc[rg][1][rr] + bb[1];
            float x2 = acc[rg][2][rr] + bb[2];
            float x3 = acc[rg][3][rr] + bb[3];
            float g0 = __builtin_amdgcn_exp2f(x0 * x0 * np[0]);
            float g1 = __builtin_amdgcn_exp2f(x1 * x1 * np[1]);
            float g2 = __builtin_amdgcn_exp2f(x2 * x2 * np[2]);
            float g3 = __builtin_amdgcn_exp2f(x3 * x3 * np[3]);
            uint2v v;
            v[0] = pk_bf16(g0, g1);
            v[1] = pk_bf16(g2, g3);
            av[rg][rr] = v;
        }
    if (presync) __syncthreads();   // all reads of hdst done before overwrite
#pragma unroll
    for (int rg = 0; rg < 4; ++rg) {
        int rbase = rg * 16 + q * 4;
#pragma unroll
        for (int rr = 0; rr < 4; ++rr)
            *(uint2v*)&hdst[(rbase + rr) * HSTR + ce] = av[rg][rr];
    }
    __syncthreads();
}

__global__ __launch_bounds__(256, 3) void mlp_kernel(
    const float* __restrict__ pos,
    const float* __restrict__ b0, const float* __restrict__ b1,
    const float* __restrict__ b2,
    const float* __restrict__ W3, const float* __restrict__ b3,
    const unsigned short* __restrict__ Wp,
    const float* __restrict__ negc,
    float* __restrict__ out)
{
    __shared__ unsigned short h[ROWS * HSTR];   // 33792 B
    __shared__ unsigned short A0[ROWS * ASTR];  // 5120 B

    const int tid  = threadIdx.x;
    const int lane = tid & 63;
    const int wave = tid >> 6;                  // column group (0..3)
    const int i16  = lane & 15, q = lane >> 4;
    const long row0 = (long)blockIdx.x * ROWS;

    // ---- build A0: row r = [p0h,p0h,p0l, p1h,p1h,p1l, p2h,p2h,p2l, 0...] ----
    if (tid < ROWS) {
        const float* pp = pos + (row0 + tid) * 3;
        float p0 = pp[0], p1 = pp[1], p2 = pp[2];
        short h0 = (short)f2bf(p0); short l0 = (short)f2bf(p0 - bf2f((unsigned short)h0));
        short h1 = (short)f2bf(p1); short l1 = (short)f2bf(p1 - bf2f((unsigned short)h1));
        short h2 = (short)f2bf(p2); short l2 = (short)f2bf(p2 - bf2f((unsigned short)h2));
        unsigned short* arow = A0 + tid * ASTR;
        *(short8*)(arow + 0)  = short8{h0, h0, l0, h1, h1, l1, h2, h2};
        *(short8*)(arow + 8)  = short8{l2, 0, 0, 0, 0, 0, 0, 0};
        *(short8*)(arow + 16) = short8{0, 0, 0, 0, 0, 0, 0, 0};
        *(short8*)(arow + 24) = short8{0, 0, 0, 0, 0, 0, 0, 0};
    }
    __syncthreads();

    // ---- layer 0 (MFMA K=32 hi/lo), layers 1,2 ----
    layer<1, ASTR>(A0, Wp, b0, negc, h, wave, i16, q, false);
    layer<8, HSTR>(h, Wp + 8192, b1, negc + 256, h, wave, i16, q, true);
    layer<8, HSTR>(h, Wp + 73728, b2, negc + 512, h, wave, i16, q, true);

    // ---- layer 4: dot(h_row, W3) + softplus(beta=1, thr=8) ----
    {
        int r = tid >> 2, qq = tid & 3;
        const unsigned short* hrow = h + r * HSTR;
        float s = 0.0f;
#pragma unroll
        for (int i = 0; i < 8; ++i) {
            int c = (qq + 4 * i) * 8;
            short8 hv = *(const short8*)(hrow + c);
            f32x4 wA = *(const f32x4*)(W3 + c);
            f32x4 wB = *(const f32x4*)(W3 + c + 4);
#pragma unroll
            for (int jj = 0; jj < 4; ++jj) {
                s = fmaf(bf2f((unsigned short)hv[jj]), wA[jj], s);
                s = fmaf(bf2f((unsigned short)hv[4 + jj]), wB[jj], s);
            }
        }
        s += __shfl_xor(s, 1);
        s += __shfl_xor(s, 2);
        if (qq == 0) {
            float x  = s + b3[0];
            float xm = fminf(x, 8.0f);
            float e  = __builtin_amdgcn_exp2f(xm * LOG2E);
            float sp = __builtin_amdgcn_logf(1.0f + e) * LN2;
            out[row0 + r] = (x > 8.0f) ? x : sp;
        }
    }
}

extern "C" void kernel_launch(void* const* d_in, const int* in_sizes, int n_in,
                              void* d_out, int out_size, void* d_ws, size_t ws_size,
                              hipStream_t stream) {
    const float* pos = (const float*)d_in[0];
    const float* W0  = (const float*)d_in[1];
    const float* b0  = (const float*)d_in[2];
    const float* W1  = (const float*)d_in[3];
    const float* b1  = (const float*)d_in[4];
    const float* W2  = (const float*)d_in[5];
    const float* b2  = (const float*)d_in[6];
    const float* W3  = (const float*)d_in[7];
    const float* b3  = (const float*)d_in[8];
    const float* s0  = (const float*)d_in[9];
    const float* s1  = (const float*)d_in[10];
    const float* s2  = (const float*)d_in[11];

    unsigned short* wp = (unsigned short*)d_ws;              // 139264 bf16
    float* negc = (float*)((char*)d_ws + 278528);            // 768 fp32

    pack_kernel<<<544, 256, 0, stream>>>(W0, W1, W2, s0, s1, s2, wp, negc);

    int nrows = in_sizes[0] / 3;          // 1048576
    int nblk  = nrows / ROWS;             // 16384
    mlp_kernel<<<nblk, 256, 0, stream>>>(pos, b0, b1, b2, W3, b3, wp, negc,
                                         (float*)d_out);
}